// Round 9
// baseline (210.183 us; speedup 1.0000x reference)
//
#include <hip/hip_runtime.h>
#include <stdint.h>

// SSD multibox head. Round 9: R7 GEMM (overlapped 2-phase double-buffer,
// QS=36, S={2,4,2,1,1,1}, dense S-replicated partials, plain stores) with
// bf16 partial storage (halves scatter read + GEMM write traffic); scatter
// sums S bf16 partials in f32 + bias, writes float4.

#define NTH 256
#define ATOT 8732
#define LOCTOT 279424       // 8*8732*4
#define QS 36               // K-steps per block, uniform across scales
#define TOTOUT 5937760      // 8*8732*85

typedef short short8 __attribute__((ext_vector_type(8)));
typedef float f32x4 __attribute__((ext_vector_type(4)));

__device__ __forceinline__ unsigned short f2bf(float f) {
  unsigned u = __float_as_uint(f);
  u += 0x7fffu + ((u >> 16) & 1u);   // RNE
  return (unsigned short)(u >> 16);
}

__device__ __forceinline__ float bf2f(unsigned short b) {
  return __uint_as_float((unsigned)b << 16);
}

__device__ __forceinline__ void gload_lds16(const void* g, void* l) {
  __builtin_amdgcn_global_load_lds(
      (const __attribute__((address_space(1))) unsigned int*)g,
      (__attribute__((address_space(3))) unsigned int*)l, 16, 0, 0);
}

// ---------------- prep_x: NCHW f32 -> NHWC bf16 (LDS tile transpose) --------
struct PXs { const float* x; unsigned short* xh; int C, HWp, ptiles, boff; };
struct PX { PXs s[6]; };

__global__ __launch_bounds__(NTH) void prep_x(PX P) {
  __shared__ float T[64][65];
  const int bid = blockIdx.x;
  int e = 0;
  #pragma unroll
  for (int i = 1; i < 6; ++i) if (bid >= P.s[i].boff) e = i;
  const PXs sp = P.s[e];
  const int local = bid - sp.boff;
  const int p64 = local % sp.ptiles;
  const int t2  = local / sp.ptiles;
  const int Cq  = sp.C >> 6;
  const int c64 = t2 % Cq;
  const int bb  = t2 / Cq;

  const int tid = threadIdx.x;
  const int p0 = p64 << 6;
  const float* xs = sp.x + (size_t)(bb * sp.C + (c64 << 6)) * sp.HWp;
  const int tx = tid & 63, ty = tid >> 6;
  const int p = p0 + tx;
  const bool pok = p < sp.HWp;
  #pragma unroll
  for (int j = 0; j < 16; ++j) {
    int c = ty + (j << 2);
    T[c][tx] = pok ? xs[(size_t)c * sp.HWp + p] : 0.f;
  }
  __syncthreads();
  const int pl = tid >> 2, cs = (tid & 3) << 4;
  const int pg = p0 + pl;
  if (pg < sp.HWp) {
    unsigned short* dst = sp.xh + ((size_t)bb * sp.HWp + pg) * sp.C + (c64 << 6) + cs;
    short8 v0, v1;
    #pragma unroll
    for (int j = 0; j < 8; ++j) {
      v0[j] = (short)f2bf(T[cs + j][pl]);
      v1[j] = (short)f2bf(T[cs + 8 + j][pl]);
    }
    *(short8*)dst = v0;
    *(short8*)(dst + 8) = v1;
  }
}

// ---------------- prep_w: OIHW f32 -> [co][r*C+ci] bf16 (pad rows zeroed) ---
struct PWs { const float *lw, *cw; unsigned short* wp; int C, lC, Nloc, Ntot, Npad, Kp; size_t tbase; };
struct PW { PWs s[6]; };

__global__ __launch_bounds__(NTH) void prep_w(PW P) {
  const size_t g = (size_t)blockIdx.x * NTH + threadIdx.x;
  int e = 0;
  #pragma unroll
  for (int i = 1; i < 6; ++i) if (g >= P.s[i].tbase) e = i;
  const PWs sp = P.s[e];
  const size_t local = g - sp.tbase;
  const int ci = (int)(local & (size_t)(sp.C - 1));
  const int co = (int)(local >> sp.lC);
  if (co >= sp.Npad) return;
  unsigned short* dst = sp.wp + (size_t)co * sp.Kp + ci;
  if (co >= sp.Ntot) {
    #pragma unroll
    for (int r = 0; r < 9; ++r) dst[(size_t)r * sp.C] = 0;
    return;
  }
  const float* wr = (co < sp.Nloc)
      ? (sp.lw + ((size_t)co * sp.C + ci) * 9)
      : (sp.cw + ((size_t)(co - sp.Nloc) * sp.C + ci) * 9);
  float v[9];
  #pragma unroll
  for (int r = 0; r < 9; ++r) v[r] = wr[r];
  #pragma unroll
  for (int r = 0; r < 9; ++r) dst[(size_t)r * sp.C] = f2bf(v[r]);
}

// ---------------- main GEMM -------------------------------------------------
struct SG {
  const unsigned short *xh, *wp;
  unsigned short* yb;              // [S][M][Npad] bf16 partials
  int H, W, HWp, C, lCq, Cq, Kp, M, Npad, mtiles, lgS, boff;
};
struct AG { SG s[6]; const char* zeros; int gq, gr; };

__global__ __launch_bounds__(NTH) void mbox_gemm(AG P) {
  __shared__ __align__(16) unsigned short A_s[2][128 * 64];
  __shared__ __align__(16) unsigned short B_s[2][128 * 64];

  // chunked XCD swizzle: bid&7 = XCD, contiguous g-range per XCD
  const int bid = blockIdx.x;
  const int xcd = bid & 7, sidx = bid >> 3;
  const int g = (xcd < P.gr) ? xcd * (P.gq + 1) + sidx
                             : P.gr * (P.gq + 1) + (xcd - P.gr) * P.gq + sidx;

  int e = 0;
  #pragma unroll
  for (int i = 1; i < 6; ++i) if (g >= P.s[i].boff) e = i;
  const SG sp = P.s[e];
  const int gl = g - sp.boff;
  const int ks = gl & ((1 << sp.lgS) - 1);
  const int t2 = gl >> sp.lgS;
  const int mtile = t2 % sp.mtiles;
  const int ntile = t2 / sp.mtiles;         // ntile-outer: B-slice stays in L2

  const int tid = threadIdx.x, lane = tid & 63, wv = tid >> 6;
  const int wm = wv >> 1, wn = wv & 1;
  const int swz = ((lane & 7) ^ (lane >> 3)) << 4;   // byte offset, 16B chunks
  const int rsub = lane >> 3;

  // A-row geometry (4 rows per thread's wave-slice)
  int bA[4], hA[4], wA[4]; bool mok[4];
  #pragma unroll
  for (int i = 0; i < 4; ++i) {
    int row = (wv << 5) + (i << 3) + rsub;
    int mg = mtile * 128 + row;
    bool ok = mg < sp.M;
    int mc = ok ? mg : 0;
    int bb = mc / sp.HWp; int p = mc - bb * sp.HWp;
    int hh = p / sp.W;    int ww = p - hh * sp.W;
    bA[i] = bb; hA[i] = hh; wA[i] = ww; mok[i] = ok;
  }

  const int q0 = ks * QS, q1 = q0 + QS;

  const char* curB[4];
  #pragma unroll
  for (int i = 0; i < 4; ++i) {
    int row = (wv << 5) + (i << 3) + rsub;
    int nrow = ntile * 128 + row;                    // wp padded: always valid
    curB[i] = (const char*)(sp.wp + (size_t)nrow * sp.Kp + (size_t)q0 * 64) + swz;
  }

  const char* curA[4];
  auto setA = [&](int rr, int cq0) {
    int d3 = rr / 3; int dh = d3 - 1, dw = rr - d3 * 3 - 1;
    #pragma unroll
    for (int i = 0; i < 4; ++i) {
      int hh = hA[i] + dh, ww = wA[i] + dw;
      bool ok = mok[i] & ((unsigned)hh < (unsigned)sp.H) & ((unsigned)ww < (unsigned)sp.W);
      const unsigned short* base = ok
          ? sp.xh + (((size_t)bA[i] * sp.H + hh) * sp.W + ww) * sp.C + (cq0 << 6)
          : (const unsigned short*)P.zeros;
      curA[i] = (const char*)base + swz;
    }
  };

  auto stage = [&](int buf) {
    char* As = (char*)&A_s[buf][0];
    char* Bs = (char*)&B_s[buf][0];
    #pragma unroll
    for (int i = 0; i < 4; ++i)
      gload_lds16(curA[i], As + ((wv << 5) + (i << 3)) * 128);
    #pragma unroll
    for (int i = 0; i < 4; ++i)
      gload_lds16(curB[i], Bs + ((wv << 5) + (i << 3)) * 128);
  };

  f32x4 acc[4][4] = {};
  const int l15 = lane & 15, lh = lane >> 4;

  // prologue: stage q0 into buf0, advance pointers to q0+1
  setA(q0 >> sp.lCq, q0 & (sp.Cq - 1));
  stage(0);
  #pragma unroll
  for (int i = 0; i < 4; ++i) { curA[i] += 128; curB[i] += 128; }

  int cur = 0;
  for (int q = q0; q < q1; ++q) {
    __syncthreads();   // drains own vmcnt (stage issued a full phase ago) + barrier
    if (q + 1 < q1) {
      if (((q + 1) & (sp.Cq - 1)) == 0) setA((q + 1) >> sp.lCq, 0);
      stage(cur ^ 1);                       // issue q+1 loads BEFORE compute(q)
      #pragma unroll
      for (int i = 0; i < 4; ++i) { curA[i] += 128; curB[i] += 128; }
    }
    const char* As = (const char*)&A_s[cur][0];
    const char* Bs = (const char*)&B_s[cur][0];
    #pragma unroll
    for (int kk = 0; kk < 2; ++kk) {
      const int klb = ((kk << 5) + (lh << 3)) << 1;  // byte k-offset
      short8 af[4], bv[4];
      #pragma unroll
      for (int mf = 0; mf < 4; ++mf) {
        int row = (wm << 6) + (mf << 4) + l15;
        af[mf] = *(const short8*)(As + row * 128 + (klb ^ ((row & 7) << 4)));
      }
      #pragma unroll
      for (int nf = 0; nf < 4; ++nf) {
        int row = (wn << 6) + (nf << 4) + l15;
        bv[nf] = *(const short8*)(Bs + row * 128 + (klb ^ ((row & 7) << 4)));
      }
      #pragma unroll
      for (int mf = 0; mf < 4; ++mf)
        #pragma unroll
        for (int nf = 0; nf < 4; ++nf)
          acc[mf][nf] = __builtin_amdgcn_mfma_f32_16x16x32_bf16(af[mf], bv[nf], acc[mf][nf], 0, 0, 0);
    }
    cur ^= 1;
  }

  // epilogue: dense coalesced bf16 store of partial tile into ybuf[ks]
  unsigned short* yb = sp.yb + (size_t)ks * sp.M * sp.Npad;
  #pragma unroll
  for (int nf = 0; nf < 4; ++nf) {
    const int ncol = ntile * 128 + (wn << 6) + (nf << 4) + l15;
    #pragma unroll
    for (int mf = 0; mf < 4; ++mf) {
      #pragma unroll
      for (int rg = 0; rg < 4; ++rg) {
        const int mg = mtile * 128 + (wm << 6) + (mf << 4) + (lh << 2) + rg;
        if (mg < sp.M) yb[(size_t)mg * sp.Npad + ncol] = f2bf(acc[mf][nf][rg]);
      }
    }
  }
}

// ---------------- scatter: sum S bf16 partials + bias -> float4 output ------
struct SCs { const unsigned short* yb; const float *lb, *cb; int HW, nb, S, Npad, M, nb4; };
struct SC { SCs s[6]; };

__global__ __launch_bounds__(NTH) void mbox_scatter(SC P, float4* __restrict__ out4) {
  const int e4 = blockIdx.x * NTH + threadIdx.x;
  if (e4 >= TOTOUT / 4) return;
  float4 r;
  #pragma unroll
  for (int j = 0; j < 4; ++j) {
    const int e = (e4 << 2) + j;
    const bool isloc = e < LOCTOT;
    int ii, t;
    if (isloc) { ii = e & 3; t = e >> 2; }
    else { unsigned e2 = (unsigned)(e - LOCTOT); ii = (int)(e2 % 81u); t = (int)(e2 / 81u); }
    const int b = (int)((unsigned)t / (unsigned)ATOT);
    const int a = t - b * ATOT;
    const int AB[6] = {0, 5776, 7942, 8542, 8692, 8728};
    int s = 0;
    #pragma unroll
    for (int i = 1; i < 6; ++i) s += (a >= AB[i]);
    const SCs sp = P.s[s];
    const int arel = a - AB[s];
    const int rb = (int)((unsigned)arel / (unsigned)sp.HW);
    const int p = arel - rb * sp.HW;
    const int co = ii * sp.nb + rb;
    const int col = (isloc ? 0 : sp.nb4) + co;
    const int m = b * sp.HW + p;
    float v = isloc ? sp.lb[co] : sp.cb[co];
    const unsigned short* yp = sp.yb + (size_t)m * sp.Npad + col;
    const size_t stride = (size_t)sp.M * sp.Npad;
    for (int k = 0; k < sp.S; ++k) { v += bf2f(*yp); yp += stride; }
    (&r.x)[j] = v;
  }
  out4[e4] = r;
}

// ---------------- host ------------------------------------------------------
extern "C" void kernel_launch(void* const* d_in, const int* in_sizes, int n_in,
                              void* d_out, int out_size, void* d_ws, size_t ws_size,
                              hipStream_t stream) {
  static const int CH[6]  = {512, 1024, 512, 256, 256, 256};
  static const int HH[6]  = {38, 19, 10, 5, 3, 1};
  static const int NB_[6] = {4, 6, 6, 6, 4, 4};
  static const int SK[6]  = {2, 4, 2, 1, 1, 1};     // -> 36 K-steps everywhere
  static const int LGS[6] = {1, 2, 1, 0, 0, 0};

  // ws layout: [xh 0..5][wp 0..5][zeros 8KB][ybuf 0..5 bf16]  (~72 MB total)
  size_t xh_off[6], wp_off[6], yb_off[6], off = 0;
  auto al = [](size_t v) { return (v + 255) & ~(size_t)255; };
  for (int s = 0; s < 6; ++s) { xh_off[s] = off; off = al(off + (size_t)8 * HH[s] * HH[s] * CH[s] * 2); }
  for (int s = 0; s < 6; ++s) {
    wp_off[s] = off;
    int Npad = ((NB_[s] * 85 + 127) / 128) * 128;
    off = al(off + (size_t)Npad * (CH[s] * 9) * 2);
  }
  const size_t zeros_off = off; off = al(off + 8192);
  for (int s = 0; s < 6; ++s) {
    yb_off[s] = off;
    int Npad = ((NB_[s] * 85 + 127) / 128) * 128;
    off = al(off + (size_t)SK[s] * (8 * HH[s] * HH[s]) * Npad * 2);
  }
  (void)ws_size;

  char* ws = (char*)d_ws;
  (void)hipMemsetAsync(ws + zeros_off, 0, 8192, stream);

  // prep_x
  PX px; int pxb = 0;
  for (int s = 0; s < 6; ++s) {
    PXs& p = px.s[s];
    p.x = (const float*)d_in[5 * s + 0];
    p.xh = (unsigned short*)(ws + xh_off[s]);
    p.C = CH[s]; p.HWp = HH[s] * HH[s];
    p.ptiles = (p.HWp + 63) / 64;
    p.boff = pxb;
    pxb += 8 * (CH[s] >> 6) * p.ptiles;
  }
  hipLaunchKernelGGL(prep_x, dim3(pxb), dim3(NTH), 0, stream, px);

  // prep_w (zero-fills pad rows)
  PW pw; size_t tb = 0;
  for (int s = 0; s < 6; ++s) {
    PWs& p = pw.s[s];
    p.lw = (const float*)d_in[5 * s + 1];
    p.cw = (const float*)d_in[5 * s + 3];
    p.wp = (unsigned short*)(ws + wp_off[s]);
    p.C = CH[s];
    p.lC = (CH[s] == 1024) ? 10 : (CH[s] == 512 ? 9 : 8);
    p.Nloc = NB_[s] * 4; p.Ntot = NB_[s] * 85;
    p.Npad = ((p.Ntot + 127) / 128) * 128;
    p.Kp = CH[s] * 9;
    p.tbase = tb;
    tb += (size_t)p.Npad * CH[s];
  }
  hipLaunchKernelGGL(prep_w, dim3((unsigned)((tb + NTH - 1) / NTH)), dim3(NTH), 0, stream, pw);

  // gemm: uniform 36-step blocks
  AG ag; ag.zeros = ws + zeros_off;
  int G = 0;
  for (int s = 0; s < 6; ++s) {
    SG& g = ag.s[s];
    g.xh = (const unsigned short*)(ws + xh_off[s]);
    g.wp = (const unsigned short*)(ws + wp_off[s]);
    g.yb = (unsigned short*)(ws + yb_off[s]);
    g.H = HH[s]; g.W = HH[s]; g.HWp = HH[s] * HH[s];
    g.C = CH[s];
    g.Cq = CH[s] >> 6;
    g.lCq = (g.Cq == 16) ? 4 : (g.Cq == 8 ? 3 : 2);
    g.Kp = CH[s] * 9;
    g.M = 8 * g.HWp;
    g.Npad = ((NB_[s] * 85 + 127) / 128) * 128;
    g.mtiles = (g.M + 127) / 128;
    g.lgS = LGS[s];
    g.boff = G;
    G += g.mtiles * (g.Npad >> 7) * SK[s];
  }
  ag.gq = G / 8; ag.gr = G % 8;
  hipLaunchKernelGGL(mbox_gemm, dim3(G), dim3(NTH), 0, stream, ag);

  // scatter (float4 stores; LOCTOT and TOTOUT are 4-divisible)
  SC sc;
  for (int s = 0; s < 6; ++s) {
    SCs& p = sc.s[s];
    p.yb = (const unsigned short*)(ws + yb_off[s]);
    p.lb = (const float*)d_in[5 * s + 2];
    p.cb = (const float*)d_in[5 * s + 4];
    p.HW = HH[s] * HH[s];
    p.nb = NB_[s];
    p.S = SK[s];
    p.Npad = ((NB_[s] * 85 + 127) / 128) * 128;
    p.M = 8 * p.HW;
    p.nb4 = NB_[s] * 4;
  }
  hipLaunchKernelGGL(mbox_scatter, dim3((TOTOUT / 4 + NTH - 1) / NTH), dim3(NTH), 0, stream, sc, (float4*)d_out);
}

// Round 10
// 148.268 us; speedup vs baseline: 1.4176x; 1.4176x over previous
//
#include <hip/hip_runtime.h>
#include <stdint.h>

// SSD multibox head. Round 10: GEMM + ybuf exactly as R7 (fp32 [S][M][Npad]
// partials, plain stores, overlapped 2-phase double-buffer, QS=36).
// New scatter: tile-staged transpose — one block per 8 ybuf rows; coalesced
// float4 reads sum S depths into LDS; writes exploit per-(m,rb) contiguity
// (loc = float4, conf = 81-float runs), biases preloaded to LDS.

#define NTH 256
#define ATOT 8732
#define LOCTOT 279424       // 8*8732*4
#define QS 36               // K-steps per block, uniform across scales
#define TOTOUT 5937760      // 8*8732*85
#define MR 8                // ybuf rows per scatter block

typedef short short8 __attribute__((ext_vector_type(8)));
typedef float f32x4 __attribute__((ext_vector_type(4)));

__device__ __forceinline__ unsigned short f2bf(float f) {
  unsigned u = __float_as_uint(f);
  u += 0x7fffu + ((u >> 16) & 1u);   // RNE
  return (unsigned short)(u >> 16);
}

__device__ __forceinline__ void gload_lds16(const void* g, void* l) {
  __builtin_amdgcn_global_load_lds(
      (const __attribute__((address_space(1))) unsigned int*)g,
      (__attribute__((address_space(3))) unsigned int*)l, 16, 0, 0);
}

// ---------------- prep_x: NCHW f32 -> NHWC bf16 (LDS tile transpose) --------
struct PXs { const float* x; unsigned short* xh; int C, HWp, ptiles, boff; };
struct PX { PXs s[6]; };

__global__ __launch_bounds__(NTH) void prep_x(PX P) {
  __shared__ float T[64][65];
  const int bid = blockIdx.x;
  int e = 0;
  #pragma unroll
  for (int i = 1; i < 6; ++i) if (bid >= P.s[i].boff) e = i;
  const PXs sp = P.s[e];
  const int local = bid - sp.boff;
  const int p64 = local % sp.ptiles;
  const int t2  = local / sp.ptiles;
  const int Cq  = sp.C >> 6;
  const int c64 = t2 % Cq;
  const int bb  = t2 / Cq;

  const int tid = threadIdx.x;
  const int p0 = p64 << 6;
  const float* xs = sp.x + (size_t)(bb * sp.C + (c64 << 6)) * sp.HWp;
  const int tx = tid & 63, ty = tid >> 6;
  const int p = p0 + tx;
  const bool pok = p < sp.HWp;
  #pragma unroll
  for (int j = 0; j < 16; ++j) {
    int c = ty + (j << 2);
    T[c][tx] = pok ? xs[(size_t)c * sp.HWp + p] : 0.f;
  }
  __syncthreads();
  const int pl = tid >> 2, cs = (tid & 3) << 4;
  const int pg = p0 + pl;
  if (pg < sp.HWp) {
    unsigned short* dst = sp.xh + ((size_t)bb * sp.HWp + pg) * sp.C + (c64 << 6) + cs;
    short8 v0, v1;
    #pragma unroll
    for (int j = 0; j < 8; ++j) {
      v0[j] = (short)f2bf(T[cs + j][pl]);
      v1[j] = (short)f2bf(T[cs + 8 + j][pl]);
    }
    *(short8*)dst = v0;
    *(short8*)(dst + 8) = v1;
  }
}

// ---------------- prep_w: OIHW f32 -> [co][r*C+ci] bf16 (pad rows zeroed) ---
struct PWs { const float *lw, *cw; unsigned short* wp; int C, lC, Nloc, Ntot, Npad, Kp; size_t tbase; };
struct PW { PWs s[6]; };

__global__ __launch_bounds__(NTH) void prep_w(PW P) {
  const size_t g = (size_t)blockIdx.x * NTH + threadIdx.x;
  int e = 0;
  #pragma unroll
  for (int i = 1; i < 6; ++i) if (g >= P.s[i].tbase) e = i;
  const PWs sp = P.s[e];
  const size_t local = g - sp.tbase;
  const int ci = (int)(local & (size_t)(sp.C - 1));
  const int co = (int)(local >> sp.lC);
  if (co >= sp.Npad) return;
  unsigned short* dst = sp.wp + (size_t)co * sp.Kp + ci;
  if (co >= sp.Ntot) {
    #pragma unroll
    for (int r = 0; r < 9; ++r) dst[(size_t)r * sp.C] = 0;
    return;
  }
  const float* wr = (co < sp.Nloc)
      ? (sp.lw + ((size_t)co * sp.C + ci) * 9)
      : (sp.cw + ((size_t)(co - sp.Nloc) * sp.C + ci) * 9);
  float v[9];
  #pragma unroll
  for (int r = 0; r < 9; ++r) v[r] = wr[r];
  #pragma unroll
  for (int r = 0; r < 9; ++r) dst[(size_t)r * sp.C] = f2bf(v[r]);
}

// ---------------- main GEMM (identical to R7) -------------------------------
struct SG {
  const unsigned short *xh, *wp;
  float* yb;                       // [S][M][Npad] fp32 partials
  int H, W, HWp, C, lCq, Cq, Kp, M, Npad, mtiles, lgS, boff;
};
struct AG { SG s[6]; const char* zeros; int gq, gr; };

__global__ __launch_bounds__(NTH) void mbox_gemm(AG P) {
  __shared__ __align__(16) unsigned short A_s[2][128 * 64];
  __shared__ __align__(16) unsigned short B_s[2][128 * 64];

  const int bid = blockIdx.x;
  const int xcd = bid & 7, sidx = bid >> 3;
  const int g = (xcd < P.gr) ? xcd * (P.gq + 1) + sidx
                             : P.gr * (P.gq + 1) + (xcd - P.gr) * P.gq + sidx;

  int e = 0;
  #pragma unroll
  for (int i = 1; i < 6; ++i) if (g >= P.s[i].boff) e = i;
  const SG sp = P.s[e];
  const int gl = g - sp.boff;
  const int ks = gl & ((1 << sp.lgS) - 1);
  const int t2 = gl >> sp.lgS;
  const int mtile = t2 % sp.mtiles;
  const int ntile = t2 / sp.mtiles;

  const int tid = threadIdx.x, lane = tid & 63, wv = tid >> 6;
  const int wm = wv >> 1, wn = wv & 1;
  const int swz = ((lane & 7) ^ (lane >> 3)) << 4;
  const int rsub = lane >> 3;

  int bA[4], hA[4], wA[4]; bool mok[4];
  #pragma unroll
  for (int i = 0; i < 4; ++i) {
    int row = (wv << 5) + (i << 3) + rsub;
    int mg = mtile * 128 + row;
    bool ok = mg < sp.M;
    int mc = ok ? mg : 0;
    int bb = mc / sp.HWp; int p = mc - bb * sp.HWp;
    int hh = p / sp.W;    int ww = p - hh * sp.W;
    bA[i] = bb; hA[i] = hh; wA[i] = ww; mok[i] = ok;
  }

  const int q0 = ks * QS, q1 = q0 + QS;

  const char* curB[4];
  #pragma unroll
  for (int i = 0; i < 4; ++i) {
    int row = (wv << 5) + (i << 3) + rsub;
    int nrow = ntile * 128 + row;
    curB[i] = (const char*)(sp.wp + (size_t)nrow * sp.Kp + (size_t)q0 * 64) + swz;
  }

  const char* curA[4];
  auto setA = [&](int rr, int cq0) {
    int d3 = rr / 3; int dh = d3 - 1, dw = rr - d3 * 3 - 1;
    #pragma unroll
    for (int i = 0; i < 4; ++i) {
      int hh = hA[i] + dh, ww = wA[i] + dw;
      bool ok = mok[i] & ((unsigned)hh < (unsigned)sp.H) & ((unsigned)ww < (unsigned)sp.W);
      const unsigned short* base = ok
          ? sp.xh + (((size_t)bA[i] * sp.H + hh) * sp.W + ww) * sp.C + (cq0 << 6)
          : (const unsigned short*)P.zeros;
      curA[i] = (const char*)base + swz;
    }
  };

  auto stage = [&](int buf) {
    char* As = (char*)&A_s[buf][0];
    char* Bs = (char*)&B_s[buf][0];
    #pragma unroll
    for (int i = 0; i < 4; ++i)
      gload_lds16(curA[i], As + ((wv << 5) + (i << 3)) * 128);
    #pragma unroll
    for (int i = 0; i < 4; ++i)
      gload_lds16(curB[i], Bs + ((wv << 5) + (i << 3)) * 128);
  };

  f32x4 acc[4][4] = {};
  const int l15 = lane & 15, lh = lane >> 4;

  setA(q0 >> sp.lCq, q0 & (sp.Cq - 1));
  stage(0);
  #pragma unroll
  for (int i = 0; i < 4; ++i) { curA[i] += 128; curB[i] += 128; }

  int cur = 0;
  for (int q = q0; q < q1; ++q) {
    __syncthreads();
    if (q + 1 < q1) {
      if (((q + 1) & (sp.Cq - 1)) == 0) setA((q + 1) >> sp.lCq, 0);
      stage(cur ^ 1);
      #pragma unroll
      for (int i = 0; i < 4; ++i) { curA[i] += 128; curB[i] += 128; }
    }
    const char* As = (const char*)&A_s[cur][0];
    const char* Bs = (const char*)&B_s[cur][0];
    #pragma unroll
    for (int kk = 0; kk < 2; ++kk) {
      const int klb = ((kk << 5) + (lh << 3)) << 1;
      short8 af[4], bv[4];
      #pragma unroll
      for (int mf = 0; mf < 4; ++mf) {
        int row = (wm << 6) + (mf << 4) + l15;
        af[mf] = *(const short8*)(As + row * 128 + (klb ^ ((row & 7) << 4)));
      }
      #pragma unroll
      for (int nf = 0; nf < 4; ++nf) {
        int row = (wn << 6) + (nf << 4) + l15;
        bv[nf] = *(const short8*)(Bs + row * 128 + (klb ^ ((row & 7) << 4)));
      }
      #pragma unroll
      for (int mf = 0; mf < 4; ++mf)
        #pragma unroll
        for (int nf = 0; nf < 4; ++nf)
          acc[mf][nf] = __builtin_amdgcn_mfma_f32_16x16x32_bf16(af[mf], bv[nf], acc[mf][nf], 0, 0, 0);
    }
    cur ^= 1;
  }

  float* yb = sp.yb + (size_t)ks * sp.M * sp.Npad;
  #pragma unroll
  for (int nf = 0; nf < 4; ++nf) {
    const int ncol = ntile * 128 + (wn << 6) + (nf << 4) + l15;
    #pragma unroll
    for (int mf = 0; mf < 4; ++mf) {
      #pragma unroll
      for (int rg = 0; rg < 4; ++rg) {
        const int mg = mtile * 128 + (wm << 6) + (mf << 4) + (lh << 2) + rg;
        if (mg < sp.M) yb[(size_t)mg * sp.Npad + ncol] = acc[mf][nf][rg];
      }
    }
  }
}

// ---------------- scatter: tile-staged transpose ----------------------------
// One block per MR=8 ybuf rows of one scale. Coalesced float4 reads sum S
// depths into LDS; writes use per-(m,rb) output contiguity.
struct SC2s { const float *yb, *lb, *cb; int HW, nb, S, Npad, M, abase, boff; };
struct SC2 { SC2s s[6]; };

__global__ __launch_bounds__(NTH) void mbox_scatter(SC2 P, float* __restrict__ out) {
  __shared__ float T[MR * 512];     // summed tile, row stride = Npad (<=512)
  __shared__ float LB[32], CB[512];
  const int bid = blockIdx.x;
  int e = 0;
  #pragma unroll
  for (int i = 1; i < 6; ++i) if (bid >= P.s[i].boff) e = i;
  const SC2s sp = P.s[e];
  const int m0 = (bid - sp.boff) * MR;
  const int tid = threadIdx.x;
  const int HW = sp.HW, nb = sp.nb, Npad = sp.Npad;
  const int nb4v = nb * 4;

  // preload biases
  for (int i = tid; i < nb4v; i += NTH) LB[i] = sp.lb[i];
  for (int i = tid; i < nb * 81; i += NTH) CB[i] = sp.cb[i];

  // load + sum S depths (coalesced float4 along Npad)
  const int np4 = Npad >> 2;
  const int tot4 = MR * np4;
  const size_t dstride4 = (size_t)sp.M * np4;
  const float4* yb4 = (const float4*)sp.yb + (size_t)m0 * np4;
  float4* T4 = (float4*)T;
  for (int idx = tid; idx < tot4; idx += NTH) {
    const float4* p = yb4 + idx;
    float4 v = *p;
    for (int k = 1; k < sp.S; ++k) {
      p += dstride4;
      float4 w = *p;
      v.x += w.x; v.y += w.y; v.z += w.z; v.w += w.w;
    }
    T4[idx] = v;
  }
  __syncthreads();

  // loc: one float4 per (mloc, rb)
  if (tid < MR * nb) {
    const int mloc = tid / nb, rb = tid - (tid / nb) * nb;
    const int m = m0 + mloc;
    const int b = m / HW, p = m - b * HW;
    const int aidx = sp.abase + rb * HW + p;
    float4 v;
    #pragma unroll
    for (int ii = 0; ii < 4; ++ii)
      (&v.x)[ii] = T[mloc * Npad + ii * nb + rb] + LB[ii * nb + rb];
    ((float4*)out)[(size_t)b * ATOT + aidx] = v;
  }

  // conf: 81-float contiguous runs per (mloc, rb)
  const int totc = MR * nb * 81;
  float* outc = out + LOCTOT;
  for (int f = tid; f < totc; f += NTH) {
    const int ii = f % 81;
    const int gg = f / 81;
    const int rb = gg % nb;
    const int mloc = gg / nb;
    const int m = m0 + mloc;
    const int b = m / HW, p = m - b * HW;
    const int aidx = sp.abase + rb * HW + p;
    const int c = ii * nb + rb;
    outc[((size_t)b * ATOT + aidx) * 81 + ii] = T[mloc * Npad + nb4v + c] + CB[c];
  }
}

// ---------------- host ------------------------------------------------------
extern "C" void kernel_launch(void* const* d_in, const int* in_sizes, int n_in,
                              void* d_out, int out_size, void* d_ws, size_t ws_size,
                              hipStream_t stream) {
  static const int CH[6]  = {512, 1024, 512, 256, 256, 256};
  static const int HH[6]  = {38, 19, 10, 5, 3, 1};
  static const int NB_[6] = {4, 6, 6, 6, 4, 4};
  static const int SK[6]  = {2, 4, 2, 1, 1, 1};     // -> 36 K-steps everywhere
  static const int LGS[6] = {1, 2, 1, 0, 0, 0};

  int abase[6]; { int a = 0; for (int s = 0; s < 6; ++s) { abase[s] = a; a += NB_[s] * HH[s] * HH[s]; } }

  // ws layout: [xh 0..5][wp 0..5][zeros 8KB][ybuf 0..5 fp32]  (~106 MB total)
  size_t xh_off[6], wp_off[6], yb_off[6], off = 0;
  auto al = [](size_t v) { return (v + 255) & ~(size_t)255; };
  for (int s = 0; s < 6; ++s) { xh_off[s] = off; off = al(off + (size_t)8 * HH[s] * HH[s] * CH[s] * 2); }
  for (int s = 0; s < 6; ++s) {
    wp_off[s] = off;
    int Npad = ((NB_[s] * 85 + 127) / 128) * 128;
    off = al(off + (size_t)Npad * (CH[s] * 9) * 2);
  }
  const size_t zeros_off = off; off = al(off + 8192);
  for (int s = 0; s < 6; ++s) {
    yb_off[s] = off;
    int Npad = ((NB_[s] * 85 + 127) / 128) * 128;
    off = al(off + (size_t)SK[s] * (8 * HH[s] * HH[s]) * Npad * 4);
  }
  (void)ws_size;

  char* ws = (char*)d_ws;
  (void)hipMemsetAsync(ws + zeros_off, 0, 8192, stream);

  // prep_x
  PX px; int pxb = 0;
  for (int s = 0; s < 6; ++s) {
    PXs& p = px.s[s];
    p.x = (const float*)d_in[5 * s + 0];
    p.xh = (unsigned short*)(ws + xh_off[s]);
    p.C = CH[s]; p.HWp = HH[s] * HH[s];
    p.ptiles = (p.HWp + 63) / 64;
    p.boff = pxb;
    pxb += 8 * (CH[s] >> 6) * p.ptiles;
  }
  hipLaunchKernelGGL(prep_x, dim3(pxb), dim3(NTH), 0, stream, px);

  // prep_w (zero-fills pad rows)
  PW pw; size_t tb = 0;
  for (int s = 0; s < 6; ++s) {
    PWs& p = pw.s[s];
    p.lw = (const float*)d_in[5 * s + 1];
    p.cw = (const float*)d_in[5 * s + 3];
    p.wp = (unsigned short*)(ws + wp_off[s]);
    p.C = CH[s];
    p.lC = (CH[s] == 1024) ? 10 : (CH[s] == 512 ? 9 : 8);
    p.Nloc = NB_[s] * 4; p.Ntot = NB_[s] * 85;
    p.Npad = ((p.Ntot + 127) / 128) * 128;
    p.Kp = CH[s] * 9;
    p.tbase = tb;
    tb += (size_t)p.Npad * CH[s];
  }
  hipLaunchKernelGGL(prep_w, dim3((unsigned)((tb + NTH - 1) / NTH)), dim3(NTH), 0, stream, pw);

  // gemm: uniform 36-step blocks
  AG ag; ag.zeros = ws + zeros_off;
  int G = 0;
  for (int s = 0; s < 6; ++s) {
    SG& g = ag.s[s];
    g.xh = (const unsigned short*)(ws + xh_off[s]);
    g.wp = (const unsigned short*)(ws + wp_off[s]);
    g.yb = (float*)(ws + yb_off[s]);
    g.H = HH[s]; g.W = HH[s]; g.HWp = HH[s] * HH[s];
    g.C = CH[s];
    g.Cq = CH[s] >> 6;
    g.lCq = (g.Cq == 16) ? 4 : (g.Cq == 8 ? 3 : 2);
    g.Kp = CH[s] * 9;
    g.M = 8 * g.HWp;
    g.Npad = ((NB_[s] * 85 + 127) / 128) * 128;
    g.mtiles = (g.M + 127) / 128;
    g.lgS = LGS[s];
    g.boff = G;
    G += g.mtiles * (g.Npad >> 7) * SK[s];
  }
  ag.gq = G / 8; ag.gr = G % 8;
  hipLaunchKernelGGL(mbox_gemm, dim3(G), dim3(NTH), 0, stream, ag);

  // scatter: one block per 8 ybuf rows (all M divisible by 8)
  SC2 sc; int SB = 0;
  for (int s = 0; s < 6; ++s) {
    SC2s& p = sc.s[s];
    p.yb = (const float*)(ws + yb_off[s]);
    p.lb = (const float*)d_in[5 * s + 2];
    p.cb = (const float*)d_in[5 * s + 4];
    p.HW = HH[s] * HH[s];
    p.nb = NB_[s];
    p.S = SK[s];
    p.Npad = ((NB_[s] * 85 + 127) / 128) * 128;
    p.M = 8 * p.HW;
    p.abase = abase[s];
    p.boff = SB;
    SB += p.M / MR;
  }
  hipLaunchKernelGGL(mbox_scatter, dim3(SB), dim3(NTH), 0, stream, sc, (float*)d_out);
}

// Round 11
// 138.312 us; speedup vs baseline: 1.5196x; 1.0720x over previous
//
#include <hip/hip_runtime.h>
#include <stdint.h>

// SSD multibox head. Round 11: R10 GEMM loop unchanged (overlapped 2-phase
// double-buffer, QS=36, S={2,4,2,1,1,1}). Changes: (1) ybuf partials stored
// bf16 (halves scatter read + GEMM write traffic; scatter reads stay
// coalesced ushort8, sums in fp32); (2) prep_x + prep_w merged into one
// kernel launch (block-range split).

#define NTH 256
#define ATOT 8732
#define LOCTOT 279424       // 8*8732*4
#define QS 36               // K-steps per block, uniform across scales
#define TOTOUT 5937760      // 8*8732*85
#define MR 8                // ybuf rows per scatter block

typedef short short8 __attribute__((ext_vector_type(8)));
typedef unsigned short ushort8 __attribute__((ext_vector_type(8)));
typedef float f32x4 __attribute__((ext_vector_type(4)));

__device__ __forceinline__ unsigned short f2bf(float f) {
  unsigned u = __float_as_uint(f);
  u += 0x7fffu + ((u >> 16) & 1u);   // RNE
  return (unsigned short)(u >> 16);
}

__device__ __forceinline__ float bf2f(unsigned short b) {
  return __uint_as_float((unsigned)b << 16);
}

__device__ __forceinline__ void gload_lds16(const void* g, void* l) {
  __builtin_amdgcn_global_load_lds(
      (const __attribute__((address_space(1))) unsigned int*)g,
      (__attribute__((address_space(3))) unsigned int*)l, 16, 0, 0);
}

// ---------------- merged prep: x-transpose blocks then w-repack blocks ------
struct PXs { const float* x; unsigned short* xh; int C, HWp, ptiles, boff; };
struct PWs { const float *lw, *cw; unsigned short* wp; int C, lC, Nloc, Ntot, Npad, Kp; size_t tbase; };
struct PREP { PXs x[6]; PWs w[6]; int pxb; };

__global__ __launch_bounds__(NTH) void prep_all(PREP P) {
  __shared__ float T[64][65];
  const int tid = threadIdx.x;
  if ((int)blockIdx.x < P.pxb) {
    // ---- prep_x: NCHW f32 -> NHWC bf16 (LDS tile transpose) ----
    const int bid = blockIdx.x;
    int e = 0;
    #pragma unroll
    for (int i = 1; i < 6; ++i) if (bid >= P.x[i].boff) e = i;
    const PXs sp = P.x[e];
    const int local = bid - sp.boff;
    const int p64 = local % sp.ptiles;
    const int t2  = local / sp.ptiles;
    const int Cq  = sp.C >> 6;
    const int c64 = t2 % Cq;
    const int bb  = t2 / Cq;

    const int p0 = p64 << 6;
    const float* xs = sp.x + (size_t)(bb * sp.C + (c64 << 6)) * sp.HWp;
    const int tx = tid & 63, ty = tid >> 6;
    const int p = p0 + tx;
    const bool pok = p < sp.HWp;
    #pragma unroll
    for (int j = 0; j < 16; ++j) {
      int c = ty + (j << 2);
      T[c][tx] = pok ? xs[(size_t)c * sp.HWp + p] : 0.f;
    }
    __syncthreads();
    const int pl = tid >> 2, cs = (tid & 3) << 4;
    const int pg = p0 + pl;
    if (pg < sp.HWp) {
      unsigned short* dst = sp.xh + ((size_t)bb * sp.HWp + pg) * sp.C + (c64 << 6) + cs;
      short8 v0, v1;
      #pragma unroll
      for (int j = 0; j < 8; ++j) {
        v0[j] = (short)f2bf(T[cs + j][pl]);
        v1[j] = (short)f2bf(T[cs + 8 + j][pl]);
      }
      *(short8*)dst = v0;
      *(short8*)(dst + 8) = v1;
    }
  } else {
    // ---- prep_w: OIHW f32 -> [co][r*C+ci] bf16 (pad rows zeroed) ----
    const size_t g = (size_t)(blockIdx.x - P.pxb) * NTH + tid;
    int e = 0;
    #pragma unroll
    for (int i = 1; i < 6; ++i) if (g >= P.w[i].tbase) e = i;
    const PWs sp = P.w[e];
    const size_t local = g - sp.tbase;
    const int ci = (int)(local & (size_t)(sp.C - 1));
    const int co = (int)(local >> sp.lC);
    if (co >= sp.Npad) return;
    unsigned short* dst = sp.wp + (size_t)co * sp.Kp + ci;
    if (co >= sp.Ntot) {
      #pragma unroll
      for (int r = 0; r < 9; ++r) dst[(size_t)r * sp.C] = 0;
      return;
    }
    const float* wr = (co < sp.Nloc)
        ? (sp.lw + ((size_t)co * sp.C + ci) * 9)
        : (sp.cw + ((size_t)(co - sp.Nloc) * sp.C + ci) * 9);
    float v[9];
    #pragma unroll
    for (int r = 0; r < 9; ++r) v[r] = wr[r];
    #pragma unroll
    for (int r = 0; r < 9; ++r) dst[(size_t)r * sp.C] = f2bf(v[r]);
  }
}

// ---------------- main GEMM (loop identical to R7/R10) ----------------------
struct SG {
  const unsigned short *xh, *wp;
  unsigned short* yb;              // [S][M][Npad] bf16 partials
  int H, W, HWp, C, lCq, Cq, Kp, M, Npad, mtiles, lgS, boff;
};
struct AG { SG s[6]; const char* zeros; int gq, gr; };

__global__ __launch_bounds__(NTH) void mbox_gemm(AG P) {
  __shared__ __align__(16) unsigned short A_s[2][128 * 64];
  __shared__ __align__(16) unsigned short B_s[2][128 * 64];

  const int bid = blockIdx.x;
  const int xcd = bid & 7, sidx = bid >> 3;
  const int g = (xcd < P.gr) ? xcd * (P.gq + 1) + sidx
                             : P.gr * (P.gq + 1) + (xcd - P.gr) * P.gq + sidx;

  int e = 0;
  #pragma unroll
  for (int i = 1; i < 6; ++i) if (g >= P.s[i].boff) e = i;
  const SG sp = P.s[e];
  const int gl = g - sp.boff;
  const int ks = gl & ((1 << sp.lgS) - 1);
  const int t2 = gl >> sp.lgS;
  const int mtile = t2 % sp.mtiles;
  const int ntile = t2 / sp.mtiles;

  const int tid = threadIdx.x, lane = tid & 63, wv = tid >> 6;
  const int wm = wv >> 1, wn = wv & 1;
  const int swz = ((lane & 7) ^ (lane >> 3)) << 4;
  const int rsub = lane >> 3;

  int bA[4], hA[4], wA[4]; bool mok[4];
  #pragma unroll
  for (int i = 0; i < 4; ++i) {
    int row = (wv << 5) + (i << 3) + rsub;
    int mg = mtile * 128 + row;
    bool ok = mg < sp.M;
    int mc = ok ? mg : 0;
    int bb = mc / sp.HWp; int p = mc - bb * sp.HWp;
    int hh = p / sp.W;    int ww = p - hh * sp.W;
    bA[i] = bb; hA[i] = hh; wA[i] = ww; mok[i] = ok;
  }

  const int q0 = ks * QS, q1 = q0 + QS;

  const char* curB[4];
  #pragma unroll
  for (int i = 0; i < 4; ++i) {
    int row = (wv << 5) + (i << 3) + rsub;
    int nrow = ntile * 128 + row;
    curB[i] = (const char*)(sp.wp + (size_t)nrow * sp.Kp + (size_t)q0 * 64) + swz;
  }

  const char* curA[4];
  auto setA = [&](int rr, int cq0) {
    int d3 = rr / 3; int dh = d3 - 1, dw = rr - d3 * 3 - 1;
    #pragma unroll
    for (int i = 0; i < 4; ++i) {
      int hh = hA[i] + dh, ww = wA[i] + dw;
      bool ok = mok[i] & ((unsigned)hh < (unsigned)sp.H) & ((unsigned)ww < (unsigned)sp.W);
      const unsigned short* base = ok
          ? sp.xh + (((size_t)bA[i] * sp.H + hh) * sp.W + ww) * sp.C + (cq0 << 6)
          : (const unsigned short*)P.zeros;
      curA[i] = (const char*)base + swz;
    }
  };

  auto stage = [&](int buf) {
    char* As = (char*)&A_s[buf][0];
    char* Bs = (char*)&B_s[buf][0];
    #pragma unroll
    for (int i = 0; i < 4; ++i)
      gload_lds16(curA[i], As + ((wv << 5) + (i << 3)) * 128);
    #pragma unroll
    for (int i = 0; i < 4; ++i)
      gload_lds16(curB[i], Bs + ((wv << 5) + (i << 3)) * 128);
  };

  f32x4 acc[4][4] = {};
  const int l15 = lane & 15, lh = lane >> 4;

  setA(q0 >> sp.lCq, q0 & (sp.Cq - 1));
  stage(0);
  #pragma unroll
  for (int i = 0; i < 4; ++i) { curA[i] += 128; curB[i] += 128; }

  int cur = 0;
  for (int q = q0; q < q1; ++q) {
    __syncthreads();
    if (q + 1 < q1) {
      if (((q + 1) & (sp.Cq - 1)) == 0) setA((q + 1) >> sp.lCq, 0);
      stage(cur ^ 1);
      #pragma unroll
      for (int i = 0; i < 4; ++i) { curA[i] += 128; curB[i] += 128; }
    }
    const char* As = (const char*)&A_s[cur][0];
    const char* Bs = (const char*)&B_s[cur][0];
    #pragma unroll
    for (int kk = 0; kk < 2; ++kk) {
      const int klb = ((kk << 5) + (lh << 3)) << 1;
      short8 af[4], bv[4];
      #pragma unroll
      for (int mf = 0; mf < 4; ++mf) {
        int row = (wm << 6) + (mf << 4) + l15;
        af[mf] = *(const short8*)(As + row * 128 + (klb ^ ((row & 7) << 4)));
      }
      #pragma unroll
      for (int nf = 0; nf < 4; ++nf) {
        int row = (wn << 6) + (nf << 4) + l15;
        bv[nf] = *(const short8*)(Bs + row * 128 + (klb ^ ((row & 7) << 4)));
      }
      #pragma unroll
      for (int mf = 0; mf < 4; ++mf)
        #pragma unroll
        for (int nf = 0; nf < 4; ++nf)
          acc[mf][nf] = __builtin_amdgcn_mfma_f32_16x16x32_bf16(af[mf], bv[nf], acc[mf][nf], 0, 0, 0);
    }
    cur ^= 1;
  }

  // epilogue: dense coalesced bf16 store of partial tile into ybuf[ks]
  unsigned short* yb = sp.yb + (size_t)ks * sp.M * sp.Npad;
  #pragma unroll
  for (int nf = 0; nf < 4; ++nf) {
    const int ncol = ntile * 128 + (wn << 6) + (nf << 4) + l15;
    #pragma unroll
    for (int mf = 0; mf < 4; ++mf) {
      #pragma unroll
      for (int rg = 0; rg < 4; ++rg) {
        const int mg = mtile * 128 + (wm << 6) + (mf << 4) + (lh << 2) + rg;
        if (mg < sp.M) yb[(size_t)mg * sp.Npad + ncol] = f2bf(acc[mf][nf][rg]);
      }
    }
  }
}

// ---------------- scatter: tile-staged transpose (bf16 partials) ------------
struct SC2s { const unsigned short* yb; const float *lb, *cb; int HW, nb, S, Npad, M, abase, boff; };
struct SC2 { SC2s s[6]; };

__global__ __launch_bounds__(NTH) void mbox_scatter(SC2 P, float* __restrict__ out) {
  __shared__ float T[MR * 512];     // summed tile, row stride = Npad (<=512)
  __shared__ float LB[32], CB[512];
  const int bid = blockIdx.x;
  int e = 0;
  #pragma unroll
  for (int i = 1; i < 6; ++i) if (bid >= P.s[i].boff) e = i;
  const SC2s sp = P.s[e];
  const int m0 = (bid - sp.boff) * MR;
  const int tid = threadIdx.x;
  const int HW = sp.HW, nb = sp.nb, Npad = sp.Npad;
  const int nb4v = nb * 4;

  // preload biases
  for (int i = tid; i < nb4v; i += NTH) LB[i] = sp.lb[i];
  for (int i = tid; i < nb * 81; i += NTH) CB[i] = sp.cb[i];

  // load + sum S depths (coalesced ushort8 along Npad, fp32 accumulate)
  const int np8 = Npad >> 3;
  const int tot8 = MR * np8;
  const size_t dstride8 = (size_t)sp.M * np8;      // in ushort8 units
  const ushort8* yb8 = (const ushort8*)sp.yb + (size_t)m0 * np8;
  for (int idx = tid; idx < tot8; idx += NTH) {
    float v[8] = {0.f, 0.f, 0.f, 0.f, 0.f, 0.f, 0.f, 0.f};
    const ushort8* p = yb8 + idx;
    for (int k = 0; k < sp.S; ++k) {
      ushort8 w = *p; p += dstride8;
      #pragma unroll
      for (int j = 0; j < 8; ++j) v[j] += bf2f(w[j]);
    }
    #pragma unroll
    for (int j = 0; j < 8; ++j) T[(idx << 3) + j] = v[j];
  }
  __syncthreads();

  // loc: one float4 per (mloc, rb)
  if (tid < MR * nb) {
    const int mloc = tid / nb, rb = tid - (tid / nb) * nb;
    const int m = m0 + mloc;
    const int b = m / HW, p = m - b * HW;
    const int aidx = sp.abase + rb * HW + p;
    float4 v;
    #pragma unroll
    for (int ii = 0; ii < 4; ++ii)
      (&v.x)[ii] = T[mloc * Npad + ii * nb + rb] + LB[ii * nb + rb];
    ((float4*)out)[(size_t)b * ATOT + aidx] = v;
  }

  // conf: 81-float contiguous runs per (mloc, rb)
  const int totc = MR * nb * 81;
  float* outc = out + LOCTOT;
  for (int f = tid; f < totc; f += NTH) {
    const int ii = f % 81;
    const int gg = f / 81;
    const int rb = gg % nb;
    const int mloc = gg / nb;
    const int m = m0 + mloc;
    const int b = m / HW, p = m - b * HW;
    const int aidx = sp.abase + rb * HW + p;
    const int c = ii * nb + rb;
    outc[((size_t)b * ATOT + aidx) * 81 + ii] = T[mloc * Npad + nb4v + c] + CB[c];
  }
}

// ---------------- host ------------------------------------------------------
extern "C" void kernel_launch(void* const* d_in, const int* in_sizes, int n_in,
                              void* d_out, int out_size, void* d_ws, size_t ws_size,
                              hipStream_t stream) {
  static const int CH[6]  = {512, 1024, 512, 256, 256, 256};
  static const int HH[6]  = {38, 19, 10, 5, 3, 1};
  static const int NB_[6] = {4, 6, 6, 6, 4, 4};
  static const int SK[6]  = {2, 4, 2, 1, 1, 1};     // -> 36 K-steps everywhere
  static const int LGS[6] = {1, 2, 1, 0, 0, 0};

  int abase[6]; { int a = 0; for (int s = 0; s < 6; ++s) { abase[s] = a; a += NB_[s] * HH[s] * HH[s]; } }

  // ws layout: [xh 0..5][wp 0..5][zeros 8KB][ybuf 0..5 bf16]  (~90 MB total)
  size_t xh_off[6], wp_off[6], yb_off[6], off = 0;
  auto al = [](size_t v) { return (v + 255) & ~(size_t)255; };
  for (int s = 0; s < 6; ++s) { xh_off[s] = off; off = al(off + (size_t)8 * HH[s] * HH[s] * CH[s] * 2); }
  for (int s = 0; s < 6; ++s) {
    wp_off[s] = off;
    int Npad = ((NB_[s] * 85 + 127) / 128) * 128;
    off = al(off + (size_t)Npad * (CH[s] * 9) * 2);
  }
  const size_t zeros_off = off; off = al(off + 8192);
  for (int s = 0; s < 6; ++s) {
    yb_off[s] = off;
    int Npad = ((NB_[s] * 85 + 127) / 128) * 128;
    off = al(off + (size_t)SK[s] * (8 * HH[s] * HH[s]) * Npad * 2);
  }
  (void)ws_size;

  char* ws = (char*)d_ws;
  (void)hipMemsetAsync(ws + zeros_off, 0, 8192, stream);

  // merged prep
  PREP pp; int pxb = 0;
  for (int s = 0; s < 6; ++s) {
    PXs& p = pp.x[s];
    p.x = (const float*)d_in[5 * s + 0];
    p.xh = (unsigned short*)(ws + xh_off[s]);
    p.C = CH[s]; p.HWp = HH[s] * HH[s];
    p.ptiles = (p.HWp + 63) / 64;
    p.boff = pxb;
    pxb += 8 * (CH[s] >> 6) * p.ptiles;
  }
  size_t tb = 0;
  for (int s = 0; s < 6; ++s) {
    PWs& p = pp.w[s];
    p.lw = (const float*)d_in[5 * s + 1];
    p.cw = (const float*)d_in[5 * s + 3];
    p.wp = (unsigned short*)(ws + wp_off[s]);
    p.C = CH[s];
    p.lC = (CH[s] == 1024) ? 10 : (CH[s] == 512 ? 9 : 8);
    p.Nloc = NB_[s] * 4; p.Ntot = NB_[s] * 85;
    p.Npad = ((p.Ntot + 127) / 128) * 128;
    p.Kp = CH[s] * 9;
    p.tbase = tb;
    tb += (size_t)p.Npad * CH[s];
  }
  pp.pxb = pxb;
  const int pwb = (int)((tb + NTH - 1) / NTH);
  hipLaunchKernelGGL(prep_all, dim3(pxb + pwb), dim3(NTH), 0, stream, pp);

  // gemm: uniform 36-step blocks
  AG ag; ag.zeros = ws + zeros_off;
  int G = 0;
  for (int s = 0; s < 6; ++s) {
    SG& g = ag.s[s];
    g.xh = (const unsigned short*)(ws + xh_off[s]);
    g.wp = (const unsigned short*)(ws + wp_off[s]);
    g.yb = (unsigned short*)(ws + yb_off[s]);
    g.H = HH[s]; g.W = HH[s]; g.HWp = HH[s] * HH[s];
    g.C = CH[s];
    g.Cq = CH[s] >> 6;
    g.lCq = (g.Cq == 16) ? 4 : (g.Cq == 8 ? 3 : 2);
    g.Kp = CH[s] * 9;
    g.M = 8 * g.HWp;
    g.Npad = ((NB_[s] * 85 + 127) / 128) * 128;
    g.mtiles = (g.M + 127) / 128;
    g.lgS = LGS[s];
    g.boff = G;
    G += g.mtiles * (g.Npad >> 7) * SK[s];
  }
  ag.gq = G / 8; ag.gr = G % 8;
  hipLaunchKernelGGL(mbox_gemm, dim3(G), dim3(NTH), 0, stream, ag);

  // scatter: one block per 8 ybuf rows (all M divisible by 8)
  SC2 sc; int SB = 0;
  for (int s = 0; s < 6; ++s) {
    SC2s& p = sc.s[s];
    p.yb = (const unsigned short*)(ws + yb_off[s]);
    p.lb = (const float*)d_in[5 * s + 2];
    p.cb = (const float*)d_in[5 * s + 4];
    p.HW = HH[s] * HH[s];
    p.nb = NB_[s];
    p.S = SK[s];
    p.Npad = ((NB_[s] * 85 + 127) / 128) * 128;
    p.M = 8 * p.HW;
    p.abase = abase[s];
    p.boff = SB;
    SB += p.M / MR;
  }
  hipLaunchKernelGGL(mbox_scatter, dim3(SB), dim3(NTH), 0, stream, sc, (float*)d_out);
}

// Round 12
// 134.433 us; speedup vs baseline: 1.5635x; 1.0289x over previous
//
#include <hip/hip_runtime.h>
#include <stdint.h>

// SSD multibox head. Round 12: GEMM goes to 512-thread blocks (8 waves, 2m x
// 4n wave grid, wave tile 64x32, acc[4][2], 4 gload_lds/thread) -> 16 waves/CU
// resident to hide the 2-phase barrier drain. Tile (128x128x64), QS=36,
// overlapped 2-phase double-buffer, bf16 ybuf partials, tile-transpose
// scatter: all unchanged from R11.

#define NTH 256
#define GTH 512
#define ATOT 8732
#define LOCTOT 279424       // 8*8732*4
#define QS 36               // K-steps per block, uniform across scales
#define TOTOUT 5937760      // 8*8732*85
#define MR 8                // ybuf rows per scatter block

typedef short short8 __attribute__((ext_vector_type(8)));
typedef unsigned short ushort8 __attribute__((ext_vector_type(8)));
typedef float f32x4 __attribute__((ext_vector_type(4)));

__device__ __forceinline__ unsigned short f2bf(float f) {
  unsigned u = __float_as_uint(f);
  u += 0x7fffu + ((u >> 16) & 1u);   // RNE
  return (unsigned short)(u >> 16);
}

__device__ __forceinline__ float bf2f(unsigned short b) {
  return __uint_as_float((unsigned)b << 16);
}

__device__ __forceinline__ void gload_lds16(const void* g, void* l) {
  __builtin_amdgcn_global_load_lds(
      (const __attribute__((address_space(1))) unsigned int*)g,
      (__attribute__((address_space(3))) unsigned int*)l, 16, 0, 0);
}

// ---------------- merged prep: x-transpose blocks then w-repack blocks ------
struct PXs { const float* x; unsigned short* xh; int C, HWp, ptiles, boff; };
struct PWs { const float *lw, *cw; unsigned short* wp; int C, lC, Nloc, Ntot, Npad, Kp; size_t tbase; };
struct PREP { PXs x[6]; PWs w[6]; int pxb; };

__global__ __launch_bounds__(NTH) void prep_all(PREP P) {
  __shared__ float T[64][65];
  const int tid = threadIdx.x;
  if ((int)blockIdx.x < P.pxb) {
    const int bid = blockIdx.x;
    int e = 0;
    #pragma unroll
    for (int i = 1; i < 6; ++i) if (bid >= P.x[i].boff) e = i;
    const PXs sp = P.x[e];
    const int local = bid - sp.boff;
    const int p64 = local % sp.ptiles;
    const int t2  = local / sp.ptiles;
    const int Cq  = sp.C >> 6;
    const int c64 = t2 % Cq;
    const int bb  = t2 / Cq;

    const int p0 = p64 << 6;
    const float* xs = sp.x + (size_t)(bb * sp.C + (c64 << 6)) * sp.HWp;
    const int tx = tid & 63, ty = tid >> 6;
    const int p = p0 + tx;
    const bool pok = p < sp.HWp;
    #pragma unroll
    for (int j = 0; j < 16; ++j) {
      int c = ty + (j << 2);
      T[c][tx] = pok ? xs[(size_t)c * sp.HWp + p] : 0.f;
    }
    __syncthreads();
    const int pl = tid >> 2, cs = (tid & 3) << 4;
    const int pg = p0 + pl;
    if (pg < sp.HWp) {
      unsigned short* dst = sp.xh + ((size_t)bb * sp.HWp + pg) * sp.C + (c64 << 6) + cs;
      short8 v0, v1;
      #pragma unroll
      for (int j = 0; j < 8; ++j) {
        v0[j] = (short)f2bf(T[cs + j][pl]);
        v1[j] = (short)f2bf(T[cs + 8 + j][pl]);
      }
      *(short8*)dst = v0;
      *(short8*)(dst + 8) = v1;
    }
  } else {
    const size_t g = (size_t)(blockIdx.x - P.pxb) * NTH + tid;
    int e = 0;
    #pragma unroll
    for (int i = 1; i < 6; ++i) if (g >= P.w[i].tbase) e = i;
    const PWs sp = P.w[e];
    const size_t local = g - sp.tbase;
    const int ci = (int)(local & (size_t)(sp.C - 1));
    const int co = (int)(local >> sp.lC);
    if (co >= sp.Npad) return;
    unsigned short* dst = sp.wp + (size_t)co * sp.Kp + ci;
    if (co >= sp.Ntot) {
      #pragma unroll
      for (int r = 0; r < 9; ++r) dst[(size_t)r * sp.C] = 0;
      return;
    }
    const float* wr = (co < sp.Nloc)
        ? (sp.lw + ((size_t)co * sp.C + ci) * 9)
        : (sp.cw + ((size_t)(co - sp.Nloc) * sp.C + ci) * 9);
    float v[9];
    #pragma unroll
    for (int r = 0; r < 9; ++r) v[r] = wr[r];
    #pragma unroll
    for (int r = 0; r < 9; ++r) dst[(size_t)r * sp.C] = f2bf(v[r]);
  }
}

// ---------------- main GEMM: 512 threads, 8 waves (2m x 4n) -----------------
struct SG {
  const unsigned short *xh, *wp;
  unsigned short* yb;              // [S][M][Npad] bf16 partials
  int H, W, HWp, C, lCq, Cq, Kp, M, Npad, mtiles, lgS, boff;
};
struct AG { SG s[6]; const char* zeros; int gq, gr; };

__global__ __launch_bounds__(GTH) void mbox_gemm(AG P) {
  __shared__ __align__(16) unsigned short A_s[2][128 * 64];
  __shared__ __align__(16) unsigned short B_s[2][128 * 64];

  const int bid = blockIdx.x;
  const int xcd = bid & 7, sidx = bid >> 3;
  const int g = (xcd < P.gr) ? xcd * (P.gq + 1) + sidx
                             : P.gr * (P.gq + 1) + (xcd - P.gr) * P.gq + sidx;

  int e = 0;
  #pragma unroll
  for (int i = 1; i < 6; ++i) if (g >= P.s[i].boff) e = i;
  const SG sp = P.s[e];
  const int gl = g - sp.boff;
  const int ks = gl & ((1 << sp.lgS) - 1);
  const int t2 = gl >> sp.lgS;
  const int mtile = t2 % sp.mtiles;
  const int ntile = t2 / sp.mtiles;

  const int tid = threadIdx.x, lane = tid & 63, wv = tid >> 6;   // wv 0..7
  const int wm = wv >> 2, wn = wv & 3;       // 2m x 4n wave grid
  const int swz = ((lane & 7) ^ (lane >> 3)) << 4;
  const int rsub = lane >> 3;

  // A-row geometry: 2 rows per thread (wave stages 16 A-rows + 16 B-rows)
  int bA[2], hA[2], wA[2]; bool mok[2];
  #pragma unroll
  for (int i = 0; i < 2; ++i) {
    int row = (wv << 4) + (i << 3) + rsub;
    int mg = mtile * 128 + row;
    bool ok = mg < sp.M;
    int mc = ok ? mg : 0;
    int bb = mc / sp.HWp; int p = mc - bb * sp.HWp;
    int hh = p / sp.W;    int ww = p - hh * sp.W;
    bA[i] = bb; hA[i] = hh; wA[i] = ww; mok[i] = ok;
  }

  const int q0 = ks * QS, q1 = q0 + QS;

  const char* curB[2];
  #pragma unroll
  for (int i = 0; i < 2; ++i) {
    int row = (wv << 4) + (i << 3) + rsub;
    int nrow = ntile * 128 + row;
    curB[i] = (const char*)(sp.wp + (size_t)nrow * sp.Kp + (size_t)q0 * 64) + swz;
  }

  const char* curA[2];
  auto setA = [&](int rr, int cq0) {
    int d3 = rr / 3; int dh = d3 - 1, dw = rr - d3 * 3 - 1;
    #pragma unroll
    for (int i = 0; i < 2; ++i) {
      int hh = hA[i] + dh, ww = wA[i] + dw;
      bool ok = mok[i] & ((unsigned)hh < (unsigned)sp.H) & ((unsigned)ww < (unsigned)sp.W);
      const unsigned short* base = ok
          ? sp.xh + (((size_t)bA[i] * sp.H + hh) * sp.W + ww) * sp.C + (cq0 << 6)
          : (const unsigned short*)P.zeros;
      curA[i] = (const char*)base + swz;
    }
  };

  auto stage = [&](int buf) {
    char* As = (char*)&A_s[buf][0];
    char* Bs = (char*)&B_s[buf][0];
    #pragma unroll
    for (int i = 0; i < 2; ++i)
      gload_lds16(curA[i], As + ((wv << 4) + (i << 3)) * 128);
    #pragma unroll
    for (int i = 0; i < 2; ++i)
      gload_lds16(curB[i], Bs + ((wv << 4) + (i << 3)) * 128);
  };

  f32x4 acc[4][2] = {};
  const int l15 = lane & 15, lh = lane >> 4;

  setA(q0 >> sp.lCq, q0 & (sp.Cq - 1));
  stage(0);
  #pragma unroll
  for (int i = 0; i < 2; ++i) { curA[i] += 128; curB[i] += 128; }

  int cur = 0;
  for (int q = q0; q < q1; ++q) {
    __syncthreads();
    if (q + 1 < q1) {
      if (((q + 1) & (sp.Cq - 1)) == 0) setA((q + 1) >> sp.lCq, 0);
      stage(cur ^ 1);
      #pragma unroll
      for (int i = 0; i < 2; ++i) { curA[i] += 128; curB[i] += 128; }
    }
    const char* As = (const char*)&A_s[cur][0];
    const char* Bs = (const char*)&B_s[cur][0];
    #pragma unroll
    for (int kk = 0; kk < 2; ++kk) {
      const int klb = ((kk << 5) + (lh << 3)) << 1;
      short8 af[4], bv[2];
      #pragma unroll
      for (int mf = 0; mf < 4; ++mf) {
        int row = (wm << 6) + (mf << 4) + l15;
        af[mf] = *(const short8*)(As + row * 128 + (klb ^ ((row & 7) << 4)));
      }
      #pragma unroll
      for (int nf = 0; nf < 2; ++nf) {
        int row = (wn << 5) + (nf << 4) + l15;
        bv[nf] = *(const short8*)(Bs + row * 128 + (klb ^ ((row & 7) << 4)));
      }
      #pragma unroll
      for (int mf = 0; mf < 4; ++mf)
        #pragma unroll
        for (int nf = 0; nf < 2; ++nf)
          acc[mf][nf] = __builtin_amdgcn_mfma_f32_16x16x32_bf16(af[mf], bv[nf], acc[mf][nf], 0, 0, 0);
    }
    cur ^= 1;
  }

  // epilogue: dense coalesced bf16 store of partial tile into ybuf[ks]
  unsigned short* yb = sp.yb + (size_t)ks * sp.M * sp.Npad;
  #pragma unroll
  for (int nf = 0; nf < 2; ++nf) {
    const int ncol = ntile * 128 + (wn << 5) + (nf << 4) + l15;
    #pragma unroll
    for (int mf = 0; mf < 4; ++mf) {
      #pragma unroll
      for (int rg = 0; rg < 4; ++rg) {
        const int mg = mtile * 128 + (wm << 6) + (mf << 4) + (lh << 2) + rg;
        if (mg < sp.M) yb[(size_t)mg * sp.Npad + ncol] = f2bf(acc[mf][nf][rg]);
      }
    }
  }
}

// ---------------- scatter: tile-staged transpose (bf16 partials) ------------
struct SC2s { const unsigned short* yb; const float *lb, *cb; int HW, nb, S, Npad, M, abase, boff; };
struct SC2 { SC2s s[6]; };

__global__ __launch_bounds__(NTH) void mbox_scatter(SC2 P, float* __restrict__ out) {
  __shared__ float T[MR * 512];     // summed tile, row stride = Npad (<=512)
  __shared__ float LB[32], CB[512];
  const int bid = blockIdx.x;
  int e = 0;
  #pragma unroll
  for (int i = 1; i < 6; ++i) if (bid >= P.s[i].boff) e = i;
  const SC2s sp = P.s[e];
  const int m0 = (bid - sp.boff) * MR;
  const int tid = threadIdx.x;
  const int HW = sp.HW, nb = sp.nb, Npad = sp.Npad;
  const int nb4v = nb * 4;

  for (int i = tid; i < nb4v; i += NTH) LB[i] = sp.lb[i];
  for (int i = tid; i < nb * 81; i += NTH) CB[i] = sp.cb[i];

  const int np8 = Npad >> 3;
  const int tot8 = MR * np8;
  const size_t dstride8 = (size_t)sp.M * np8;      // in ushort8 units
  const ushort8* yb8 = (const ushort8*)sp.yb + (size_t)m0 * np8;
  for (int idx = tid; idx < tot8; idx += NTH) {
    float v[8] = {0.f, 0.f, 0.f, 0.f, 0.f, 0.f, 0.f, 0.f};
    const ushort8* p = yb8 + idx;
    for (int k = 0; k < sp.S; ++k) {
      ushort8 w = *p; p += dstride8;
      #pragma unroll
      for (int j = 0; j < 8; ++j) v[j] += bf2f(w[j]);
    }
    #pragma unroll
    for (int j = 0; j < 8; ++j) T[(idx << 3) + j] = v[j];
  }
  __syncthreads();

  if (tid < MR * nb) {
    const int mloc = tid / nb, rb = tid - (tid / nb) * nb;
    const int m = m0 + mloc;
    const int b = m / HW, p = m - b * HW;
    const int aidx = sp.abase + rb * HW + p;
    float4 v;
    #pragma unroll
    for (int ii = 0; ii < 4; ++ii)
      (&v.x)[ii] = T[mloc * Npad + ii * nb + rb] + LB[ii * nb + rb];
    ((float4*)out)[(size_t)b * ATOT + aidx] = v;
  }

  const int totc = MR * nb * 81;
  float* outc = out + LOCTOT;
  for (int f = tid; f < totc; f += NTH) {
    const int ii = f % 81;
    const int gg = f / 81;
    const int rb = gg % nb;
    const int mloc = gg / nb;
    const int m = m0 + mloc;
    const int b = m / HW, p = m - b * HW;
    const int aidx = sp.abase + rb * HW + p;
    const int c = ii * nb + rb;
    outc[((size_t)b * ATOT + aidx) * 81 + ii] = T[mloc * Npad + nb4v + c] + CB[c];
  }
}

// ---------------- host ------------------------------------------------------
extern "C" void kernel_launch(void* const* d_in, const int* in_sizes, int n_in,
                              void* d_out, int out_size, void* d_ws, size_t ws_size,
                              hipStream_t stream) {
  static const int CH[6]  = {512, 1024, 512, 256, 256, 256};
  static const int HH[6]  = {38, 19, 10, 5, 3, 1};
  static const int NB_[6] = {4, 6, 6, 6, 4, 4};
  static const int SK[6]  = {2, 4, 2, 1, 1, 1};     // -> 36 K-steps everywhere
  static const int LGS[6] = {1, 2, 1, 0, 0, 0};

  int abase[6]; { int a = 0; for (int s = 0; s < 6; ++s) { abase[s] = a; a += NB_[s] * HH[s] * HH[s]; } }

  // ws layout: [xh 0..5][wp 0..5][zeros 8KB][ybuf 0..5 bf16]  (~90 MB total)
  size_t xh_off[6], wp_off[6], yb_off[6], off = 0;
  auto al = [](size_t v) { return (v + 255) & ~(size_t)255; };
  for (int s = 0; s < 6; ++s) { xh_off[s] = off; off = al(off + (size_t)8 * HH[s] * HH[s] * CH[s] * 2); }
  for (int s = 0; s < 6; ++s) {
    wp_off[s] = off;
    int Npad = ((NB_[s] * 85 + 127) / 128) * 128;
    off = al(off + (size_t)Npad * (CH[s] * 9) * 2);
  }
  const size_t zeros_off = off; off = al(off + 8192);
  for (int s = 0; s < 6; ++s) {
    yb_off[s] = off;
    int Npad = ((NB_[s] * 85 + 127) / 128) * 128;
    off = al(off + (size_t)SK[s] * (8 * HH[s] * HH[s]) * Npad * 2);
  }
  (void)ws_size;

  char* ws = (char*)d_ws;
  (void)hipMemsetAsync(ws + zeros_off, 0, 8192, stream);

  // merged prep
  PREP pp; int pxb = 0;
  for (int s = 0; s < 6; ++s) {
    PXs& p = pp.x[s];
    p.x = (const float*)d_in[5 * s + 0];
    p.xh = (unsigned short*)(ws + xh_off[s]);
    p.C = CH[s]; p.HWp = HH[s] * HH[s];
    p.ptiles = (p.HWp + 63) / 64;
    p.boff = pxb;
    pxb += 8 * (CH[s] >> 6) * p.ptiles;
  }
  size_t tb = 0;
  for (int s = 0; s < 6; ++s) {
    PWs& p = pp.w[s];
    p.lw = (const float*)d_in[5 * s + 1];
    p.cw = (const float*)d_in[5 * s + 3];
    p.wp = (unsigned short*)(ws + wp_off[s]);
    p.C = CH[s];
    p.lC = (CH[s] == 1024) ? 10 : (CH[s] == 512 ? 9 : 8);
    p.Nloc = NB_[s] * 4; p.Ntot = NB_[s] * 85;
    p.Npad = ((p.Ntot + 127) / 128) * 128;
    p.Kp = CH[s] * 9;
    p.tbase = tb;
    tb += (size_t)p.Npad * CH[s];
  }
  pp.pxb = pxb;
  const int pwb = (int)((tb + NTH - 1) / NTH);
  hipLaunchKernelGGL(prep_all, dim3(pxb + pwb), dim3(NTH), 0, stream, pp);

  // gemm: uniform 36-step blocks, 512 threads
  AG ag; ag.zeros = ws + zeros_off;
  int G = 0;
  for (int s = 0; s < 6; ++s) {
    SG& g = ag.s[s];
    g.xh = (const unsigned short*)(ws + xh_off[s]);
    g.wp = (const unsigned short*)(ws + wp_off[s]);
    g.yb = (unsigned short*)(ws + yb_off[s]);
    g.H = HH[s]; g.W = HH[s]; g.HWp = HH[s] * HH[s];
    g.C = CH[s];
    g.Cq = CH[s] >> 6;
    g.lCq = (g.Cq == 16) ? 4 : (g.Cq == 8 ? 3 : 2);
    g.Kp = CH[s] * 9;
    g.M = 8 * g.HWp;
    g.Npad = ((NB_[s] * 85 + 127) / 128) * 128;
    g.mtiles = (g.M + 127) / 128;
    g.lgS = LGS[s];
    g.boff = G;
    G += g.mtiles * (g.Npad >> 7) * SK[s];
  }
  ag.gq = G / 8; ag.gr = G % 8;
  hipLaunchKernelGGL(mbox_gemm, dim3(G), dim3(GTH), 0, stream, ag);

  // scatter: one block per 8 ybuf rows (all M divisible by 8)
  SC2 sc; int SB = 0;
  for (int s = 0; s < 6; ++s) {
    SC2s& p = sc.s[s];
    p.yb = (const unsigned short*)(ws + yb_off[s]);
    p.lb = (const float*)d_in[5 * s + 2];
    p.cb = (const float*)d_in[5 * s + 4];
    p.HW = HH[s] * HH[s];
    p.nb = NB_[s];
    p.S = SK[s];
    p.Npad = ((NB_[s] * 85 + 127) / 128) * 128;
    p.M = 8 * p.HW;
    p.abase = abase[s];
    p.boff = SB;
    SB += p.M / MR;
  }
  hipLaunchKernelGGL(mbox_scatter, dim3(SB), dim3(NTH), 0, stream, sc, (float*)d_out);
}